// Round 1
// baseline (598.502 us; speedup 1.0000x reference)
//
#include <hip/hip_runtime.h>

typedef __attribute__((ext_vector_type(8))) short short8;
typedef __attribute__((ext_vector_type(4))) float f32x4;
typedef unsigned short ushort_t;
typedef unsigned int uint_t;

#define MFMA16(a, b, c) __builtin_amdgcn_mfma_f32_16x16x32_bf16((a), (b), (c), 0, 0, 0)

constexpr int V = 10000;
constexpr int E = 640000;
constexpr int NF = 128;      // node feature dim
constexpr int XS_STRIDE = 264;  // 256 + 8 pad (bf16), keeps 16B alignment, breaks bank stride
constexpr int YS_STRIDE = 136;  // 128 + 8 pad

__device__ __forceinline__ ushort_t f2b(float f) {
    // fp32 -> bf16 round-to-nearest-even (finite inputs)
    uint_t u = __float_as_uint(f);
    u += 0x7FFFu + ((u >> 16) & 1u);
    return (ushort_t)(u >> 16);
}

__device__ __forceinline__ float silu(float x) {
    return x / (1.0f + __expf(-x));
}

__global__ void cvt_f32_bf16(const float* __restrict__ src, ushort_t* __restrict__ dst, int n) {
    int i = blockIdx.x * blockDim.x + threadIdx.x;
    if (i < n) dst[i] = f2b(src[i]);
}

// ---------------------------------------------------------------------------
// Edge kernel: for each tile of 64 edges:
//   x = concat(h[row], h[col])          [64, 256] bf16 (LDS)
//   y = silu(x @ W1 + b1)               [64, 128] bf16 (LDS)
//   m = silu(y @ W2 + b2)               [64, 128] fp32
//   mij[e] = m ; atomicAdd(agg[row[e]], m)
// Each wave owns 32 output columns; W fragments live in registers across the
// grid-stride tile loop.
// ---------------------------------------------------------------------------
__global__ __launch_bounds__(256, 2) void edge_kernel(
    const ushort_t* __restrict__ hb, const int* __restrict__ eidx,
    const ushort_t* __restrict__ w1, const float* __restrict__ eb1,
    const ushort_t* __restrict__ w2, const float* __restrict__ eb2,
    float* __restrict__ mij, float* __restrict__ agg) {
    __shared__ __align__(16) ushort_t xs[64 * XS_STRIDE];
    __shared__ __align__(16) ushort_t ys[64 * YS_STRIDE];
    __shared__ int ridx[64];

    const int tid = threadIdx.x;
    const int wave = tid >> 6;
    const int lane = tid & 63;
    const int quad = lane >> 4;
    const int ln = lane & 15;
    const int ncol0 = wave * 32;

    // Preload B fragments into registers.
    // B-operand layout (16x16x32): lane holds B[k = quad*8 + j][n = lane&15].
    short8 b1f[8][2];  // K=256 -> 8 k-steps; 2 column tiles of 16
    short8 b2f[4][2];  // K=128 -> 4 k-steps
#pragma unroll
    for (int kk = 0; kk < 8; kk++)
#pragma unroll
        for (int t = 0; t < 2; t++) {
            short8 f;
#pragma unroll
            for (int j = 0; j < 8; j++)
                f[j] = ((const short*)w1)[(kk * 32 + quad * 8 + j) * 128 + ncol0 + t * 16 + ln];
            b1f[kk][t] = f;
        }
#pragma unroll
    for (int kk = 0; kk < 4; kk++)
#pragma unroll
        for (int t = 0; t < 2; t++) {
            short8 f;
#pragma unroll
            for (int j = 0; j < 8; j++)
                f[j] = ((const short*)w2)[(kk * 32 + quad * 8 + j) * 128 + ncol0 + t * 16 + ln];
            b2f[kk][t] = f;
        }
    const float bv1[2] = {eb1[ncol0 + ln], eb1[ncol0 + 16 + ln]};
    const float bv2[2] = {eb2[ncol0 + ln], eb2[ncol0 + 16 + ln]};

    for (int tile = blockIdx.x; tile < E / 64; tile += gridDim.x) {
        const int e0 = tile * 64;
        // ---- stage x tile: 4 threads per edge, 64 bf16 per thread ----
        {
            const int e = tid >> 2, seg = tid & 3;
            const int r = eidx[e0 + e];
            const int c = eidx[E + e0 + e];
            if (seg == 0) ridx[e] = r;
            const int node = (seg < 2) ? r : c;
            const uint4* src = (const uint4*)(hb + node * 128 + (seg & 1) * 64);
            uint4* dst = (uint4*)(xs + e * XS_STRIDE + seg * 64);
#pragma unroll
            for (int u = 0; u < 8; u++) dst[u] = src[u];
        }
        __syncthreads();

        // ---- layer 1 ----
        f32x4 acc[4][2];
#pragma unroll
        for (int mt = 0; mt < 4; mt++)
#pragma unroll
            for (int t = 0; t < 2; t++) acc[mt][t] = f32x4{bv1[t], bv1[t], bv1[t], bv1[t]};
#pragma unroll
        for (int kk = 0; kk < 8; kk++) {
#pragma unroll
            for (int mt = 0; mt < 4; mt++) {
                short8 a = *(const short8*)(xs + (mt * 16 + ln) * XS_STRIDE + kk * 32 + quad * 8);
                acc[mt][0] = MFMA16(a, b1f[kk][0], acc[mt][0]);
                acc[mt][1] = MFMA16(a, b1f[kk][1], acc[mt][1]);
            }
        }
        // silu -> bf16 -> LDS (C/D layout: row = quad*4 + r, col = ln)
#pragma unroll
        for (int mt = 0; mt < 4; mt++)
#pragma unroll
            for (int t = 0; t < 2; t++) {
#pragma unroll
                for (int r = 0; r < 4; r++) {
                    float s = silu(acc[mt][t][r]);
                    ys[(mt * 16 + quad * 4 + r) * YS_STRIDE + ncol0 + t * 16 + ln] = f2b(s);
                }
            }
        __syncthreads();

        // ---- layer 2 ----
        f32x4 acc2[4][2];
#pragma unroll
        for (int mt = 0; mt < 4; mt++)
#pragma unroll
            for (int t = 0; t < 2; t++) acc2[mt][t] = f32x4{bv2[t], bv2[t], bv2[t], bv2[t]};
#pragma unroll
        for (int kk = 0; kk < 4; kk++) {
#pragma unroll
            for (int mt = 0; mt < 4; mt++) {
                short8 a = *(const short8*)(ys + (mt * 16 + ln) * YS_STRIDE + kk * 32 + quad * 8);
                acc2[mt][0] = MFMA16(a, b2f[kk][0], acc2[mt][0]);
                acc2[mt][1] = MFMA16(a, b2f[kk][1], acc2[mt][1]);
            }
        }

        // ---- epilogue: silu, store mij, scatter-add agg ----
#pragma unroll
        for (int mt = 0; mt < 4; mt++) {
#pragma unroll
            for (int r = 0; r < 4; r++) {
                const int row = mt * 16 + quad * 4 + r;
                const int nsrc = ridx[row];
#pragma unroll
                for (int t = 0; t < 2; t++) {
                    float s = silu(acc2[mt][t][r]);
                    const int col = ncol0 + t * 16 + ln;
                    mij[(size_t)(e0 + row) * 128 + col] = s;
                    unsafeAtomicAdd(&agg[nsrc * 128 + col], s);
                }
            }
        }
        __syncthreads();
    }
}

// ---------------------------------------------------------------------------
// Node kernel: a = concat(h, agg/100); out = h + silu(a @ NW1 + nb1) @ NW2 + nb2
// One 64-row tile per block; last tile partially valid.
// ---------------------------------------------------------------------------
__global__ __launch_bounds__(256, 2) void node_kernel(
    const ushort_t* __restrict__ hb, const float* __restrict__ h32,
    const float* __restrict__ agg,
    const ushort_t* __restrict__ w1, const float* __restrict__ nb1,
    const ushort_t* __restrict__ w2, const float* __restrict__ nb2,
    float* __restrict__ out) {
    __shared__ __align__(16) ushort_t xs[64 * XS_STRIDE];
    __shared__ __align__(16) ushort_t ys[64 * YS_STRIDE];

    const int tid = threadIdx.x;
    const int wave = tid >> 6;
    const int lane = tid & 63;
    const int quad = lane >> 4;
    const int ln = lane & 15;
    const int ncol0 = wave * 32;
    const int i0 = blockIdx.x * 64;

    short8 b1f[8][2];
    short8 b2f[4][2];
#pragma unroll
    for (int kk = 0; kk < 8; kk++)
#pragma unroll
        for (int t = 0; t < 2; t++) {
            short8 f;
#pragma unroll
            for (int j = 0; j < 8; j++)
                f[j] = ((const short*)w1)[(kk * 32 + quad * 8 + j) * 128 + ncol0 + t * 16 + ln];
            b1f[kk][t] = f;
        }
#pragma unroll
    for (int kk = 0; kk < 4; kk++)
#pragma unroll
        for (int t = 0; t < 2; t++) {
            short8 f;
#pragma unroll
            for (int j = 0; j < 8; j++)
                f[j] = ((const short*)w2)[(kk * 32 + quad * 8 + j) * 128 + ncol0 + t * 16 + ln];
            b2f[kk][t] = f;
        }
    const float bv1[2] = {nb1[ncol0 + ln], nb1[ncol0 + 16 + ln]};
    const float bv2[2] = {nb2[ncol0 + ln], nb2[ncol0 + 16 + ln]};

    // ---- stage: segs 0,1 = h (bf16 copy); segs 2,3 = agg * (1/100) ----
    {
        const int e = tid >> 2, seg = tid & 3;
        const int node = i0 + e;
        if (node < V) {
            if (seg < 2) {
                const uint4* src = (const uint4*)(hb + node * 128 + seg * 64);
                uint4* dst = (uint4*)(xs + e * XS_STRIDE + seg * 64);
#pragma unroll
                for (int u = 0; u < 8; u++) dst[u] = src[u];
            } else {
                const float4* src = (const float4*)(agg + node * 128 + (seg & 1) * 64);
                ushort4* dst = (ushort4*)(xs + e * XS_STRIDE + seg * 64);
#pragma unroll
                for (int u = 0; u < 16; u++) {
                    float4 v = src[u];
                    ushort4 o;
                    o.x = f2b(v.x * 0.01f);
                    o.y = f2b(v.y * 0.01f);
                    o.z = f2b(v.z * 0.01f);
                    o.w = f2b(v.w * 0.01f);
                    dst[u] = o;
                }
            }
        } else {
            uint4 z{0, 0, 0, 0};
            uint4* dst = (uint4*)(xs + e * XS_STRIDE + seg * 64);
#pragma unroll
            for (int u = 0; u < 8; u++) dst[u] = z;
        }
    }
    __syncthreads();

    // ---- layer 1 (silu) ----
    f32x4 acc[4][2];
#pragma unroll
    for (int mt = 0; mt < 4; mt++)
#pragma unroll
        for (int t = 0; t < 2; t++) acc[mt][t] = f32x4{bv1[t], bv1[t], bv1[t], bv1[t]};
#pragma unroll
    for (int kk = 0; kk < 8; kk++) {
#pragma unroll
        for (int mt = 0; mt < 4; mt++) {
            short8 a = *(const short8*)(xs + (mt * 16 + ln) * XS_STRIDE + kk * 32 + quad * 8);
            acc[mt][0] = MFMA16(a, b1f[kk][0], acc[mt][0]);
            acc[mt][1] = MFMA16(a, b1f[kk][1], acc[mt][1]);
        }
    }
#pragma unroll
    for (int mt = 0; mt < 4; mt++)
#pragma unroll
        for (int t = 0; t < 2; t++) {
#pragma unroll
            for (int r = 0; r < 4; r++) {
                float s = silu(acc[mt][t][r]);
                ys[(mt * 16 + quad * 4 + r) * YS_STRIDE + ncol0 + t * 16 + ln] = f2b(s);
            }
        }
    __syncthreads();

    // ---- layer 2 (no activation) + residual ----
    f32x4 acc2[4][2];
#pragma unroll
    for (int mt = 0; mt < 4; mt++)
#pragma unroll
        for (int t = 0; t < 2; t++) acc2[mt][t] = f32x4{bv2[t], bv2[t], bv2[t], bv2[t]};
#pragma unroll
    for (int kk = 0; kk < 4; kk++) {
#pragma unroll
        for (int mt = 0; mt < 4; mt++) {
            short8 a = *(const short8*)(ys + (mt * 16 + ln) * YS_STRIDE + kk * 32 + quad * 8);
            acc2[mt][0] = MFMA16(a, b2f[kk][0], acc2[mt][0]);
            acc2[mt][1] = MFMA16(a, b2f[kk][1], acc2[mt][1]);
        }
    }
#pragma unroll
    for (int mt = 0; mt < 4; mt++) {
#pragma unroll
        for (int r = 0; r < 4; r++) {
            const int row = mt * 16 + quad * 4 + r;
            const int node = i0 + row;
            if (node < V) {
#pragma unroll
                for (int t = 0; t < 2; t++) {
                    const int col = ncol0 + t * 16 + ln;
                    out[(size_t)node * 128 + col] = h32[(size_t)node * 128 + col] + acc2[mt][t][r];
                }
            }
        }
    }
}

extern "C" void kernel_launch(void* const* d_in, const int* in_sizes, int n_in,
                              void* d_out, int out_size, void* d_ws, size_t ws_size,
                              hipStream_t stream) {
    const float* h = (const float*)d_in[0];
    const int* eidx = (const int*)d_in[1];
    const float* ew1 = (const float*)d_in[2];
    const float* eb1 = (const float*)d_in[3];
    const float* ew2 = (const float*)d_in[4];
    const float* eb2 = (const float*)d_in[5];
    const float* nw1 = (const float*)d_in[6];
    const float* nb1 = (const float*)d_in[7];
    const float* nw2 = (const float*)d_in[8];
    const float* nb2 = (const float*)d_in[9];

    float* out = (float*)d_out;               // [V,128]
    float* mij = (float*)d_out + (size_t)V * 128;  // [E,128]

    // workspace layout
    uint8_t* ws = (uint8_t*)d_ws;
    ushort_t* hb = (ushort_t*)(ws);                         // 2,560,000 B
    ushort_t* w1b = (ushort_t*)(ws + 2560000);              // 65,536 B
    ushort_t* w2b = (ushort_t*)(ws + 2560000 + 65536);      // 32,768 B
    ushort_t* nw1b = (ushort_t*)(ws + 2560000 + 98304);     // 65,536 B
    ushort_t* nw2b = (ushort_t*)(ws + 2560000 + 163840);    // 32,768 B
    float* agg = (float*)(ws + 2560000 + 196608);           // 5,120,000 B

    hipMemsetAsync(agg, 0, (size_t)V * 128 * sizeof(float), stream);

    cvt_f32_bf16<<<(V * 128 + 255) / 256, 256, 0, stream>>>(h, hb, V * 128);
    cvt_f32_bf16<<<128, 256, 0, stream>>>(ew1, w1b, 256 * 128);
    cvt_f32_bf16<<<64, 256, 0, stream>>>(ew2, w2b, 128 * 128);
    cvt_f32_bf16<<<128, 256, 0, stream>>>(nw1, nw1b, 256 * 128);
    cvt_f32_bf16<<<64, 256, 0, stream>>>(nw2, nw2b, 128 * 128);

    edge_kernel<<<2048, 256, 0, stream>>>(hb, eidx, w1b, eb1, w2b, eb2, mij, agg);
    node_kernel<<<(V + 63) / 64, 256, 0, stream>>>(hb, h, agg, nw1b, nb1, nw2b, nb2, out);
}